// Round 3
// baseline (336.771 us; speedup 1.0000x reference)
//
#include <hip/hip_runtime.h>
#include <math.h>

// Fused Bayesian-logistic-regression sampling:
//   out[i,s] = sigmoid( sqrt(sum_j X_ij^2 * exp(lv_j)) * z_s + sum_j X_ij * mu_j )
//
// Memory-bound: 128 MB read (X) + 256 MB write (out); HBM floor ~61 us.
// R3: two phases inside one kernel.
//   Phase A: 16-lane groups reduce 64 rows/block -> (-mean*log2e, -std*log2e)
//            in LDS (512 B). Reduction latency is off the store path.
//   Phase B: all 256 threads stream the 32 KB output block with wave-contiguous
//            1 KB nontemporal stores (the proven 6.4 TB/s fill pattern).

typedef float f4 __attribute__((ext_vector_type(4)));

#define RPB 64  // rows per block

__global__ __launch_bounds__(256) void logreg_fused(
    const float* __restrict__ X,
    const float* __restrict__ w_mu,
    const float* __restrict__ w_lv,
    const float* __restrict__ z,
    float* __restrict__ out,
    int n_rows)
{
    __shared__ float s_m2[RPB];  // -mean * log2e
    __shared__ float s_s2[RPB];  // -std  * log2e

    const float NEG_LOG2E = -1.4426950408889634f;
    const int t    = threadIdx.x;
    const int row0 = blockIdx.x * RPB;
    const int nblk = min(RPB, n_rows - row0);

    // ---------------- Phase A: per-row mean/std -> LDS ----------------
    const int grp = t >> 4;      // 16 groups of 16 lanes
    const int l   = t & 15;
    const int r0  = grp * 4;     // local rows [r0, r0+4)

    const f4 mu4 = ((const f4*)w_mu)[l];
    const f4 lv4 = ((const f4*)w_lv)[l];
    f4 ev4;
    ev4.x = __expf(lv4.x); ev4.y = __expf(lv4.y);
    ev4.z = __expf(lv4.z); ev4.w = __expf(lv4.w);

    const f4* X4 = (const f4*)X;

    if (__builtin_expect(nblk == RPB, 1)) {
        // 4 independent loads issued before any use (vmcnt-overlapped).
        f4 x[4];
        #pragma unroll
        for (int j = 0; j < 4; ++j)
            x[j] = __builtin_nontemporal_load(
                &X4[(size_t)(row0 + r0 + j) * 16 + l]);

        float a[4], b[4];
        #pragma unroll
        for (int j = 0; j < 4; ++j) {
            a[j] = x[j].x * mu4.x + x[j].y * mu4.y
                 + x[j].z * mu4.z + x[j].w * mu4.w;
            b[j] = x[j].x * x[j].x * ev4.x + x[j].y * x[j].y * ev4.y
                 + x[j].z * x[j].z * ev4.z + x[j].w * x[j].w * ev4.w;
        }
        #pragma unroll
        for (int m = 1; m < 16; m <<= 1) {
            #pragma unroll
            for (int j = 0; j < 4; ++j) {
                a[j] += __shfl_xor(a[j], m, 64);
                b[j] += __shfl_xor(b[j], m, 64);
            }
        }
        if (l == 0) {
            #pragma unroll
            for (int j = 0; j < 4; ++j) {
                s_m2[r0 + j] = a[j] * NEG_LOG2E;
                s_s2[r0 + j] = sqrtf(b[j]) * NEG_LOG2E;
            }
        }
    } else {
        // Tail block (1 of 7813 at N=500000): guarded scalar path.
        for (int j = 0; j < 4; ++j) {
            const int lr = r0 + j;
            if (lr < nblk) {
                f4 x = X4[(size_t)(row0 + lr) * 16 + l];
                float a = x.x * mu4.x + x.y * mu4.y + x.z * mu4.z + x.w * mu4.w;
                float b = x.x * x.x * ev4.x + x.y * x.y * ev4.y
                        + x.z * x.z * ev4.z + x.w * x.w * ev4.w;
                for (int m = 1; m < 16; m <<= 1) {
                    a += __shfl_xor(a, m, 64);
                    b += __shfl_xor(b, m, 64);
                }
                if (l == 0) {
                    s_m2[lr] = a * NEG_LOG2E;
                    s_s2[lr] = sqrtf(b) * NEG_LOG2E;
                }
            }
        }
    }
    __syncthreads();

    // ---------------- Phase B: stream 32 KB of sigmoids ----------------
    // Thread handles f4-column (t&31) of rows (t>>5) + 8k. Per store instr:
    // lanes 0-31 = row r cols 0..127, lanes 32-63 = row r+1 -> one contiguous
    // 1 KB segment per wave (fill-kernel pattern, 6.4 TB/s proven).
    const int qcol  = t & 31;
    const int rbase = t >> 5;
    const f4 zc = ((const f4*)z)[qcol];   // loop-invariant per thread
    f4* outb = (f4*)(out + (size_t)row0 * 128);

    #pragma unroll
    for (int k = 0; k < 8; ++k) {
        const int lr = rbase + 8 * k;
        if (lr < nblk) {
            const float s2 = s_s2[lr];
            const float m2 = s_m2[lr];
            f4 o;
            o.x = __builtin_amdgcn_rcpf(1.0f + __builtin_amdgcn_exp2f(fmaf(zc.x, s2, m2)));
            o.y = __builtin_amdgcn_rcpf(1.0f + __builtin_amdgcn_exp2f(fmaf(zc.y, s2, m2)));
            o.z = __builtin_amdgcn_rcpf(1.0f + __builtin_amdgcn_exp2f(fmaf(zc.z, s2, m2)));
            o.w = __builtin_amdgcn_rcpf(1.0f + __builtin_amdgcn_exp2f(fmaf(zc.w, s2, m2)));
            __builtin_nontemporal_store(o, &outb[(size_t)lr * 32 + qcol]);
        }
    }
}

extern "C" void kernel_launch(void* const* d_in, const int* in_sizes, int n_in,
                              void* d_out, int out_size, void* d_ws, size_t ws_size,
                              hipStream_t stream) {
    const float* X    = (const float*)d_in[0];
    const float* w_mu = (const float*)d_in[1];
    const float* w_lv = (const float*)d_in[2];
    const float* z    = (const float*)d_in[3];
    float* out = (float*)d_out;

    const int n_rows = in_sizes[0] / 64;          // 500000
    const int blocks = (n_rows + RPB - 1) / RPB;  // 7813

    logreg_fused<<<blocks, 256, 0, stream>>>(X, w_mu, w_lv, z, out, n_rows);
}